// Round 5
// baseline (114.093 us; speedup 1.0000x reference)
//
#include <hip/hip_runtime.h>
#include <math.h>

// Problem constants (from reference)
#define XS 540
#define YS 540
#define NB 4            // batch
#define NBOX 64
#define TILE 36         // 36x36 cells per block
#define TPX 15          // 540 / 36
#define NTILE (TPX * TPX)       // 225
#define NBLK (NB * NTILE)       // 900
#define Q_PER_TILE (36 * 9)     // 324 float4 groups per tile
#define XS4 (XS / 4)            // 135 float4 per row

#define POISON_U32 0xAAAAAAAAu

// d_ws layout: float acc[12] = { s1[4], s2[4], cnt[4] }; uint ticket.
// No zero-init: harness poison 0xAAAAAAAA as f32 is -3.03e-13 (negligible
// additive bias on sums of O(1e4); keeps cnt>0 == false when no valid cells).
// Ticket init is 0xAAAAAAAA (or 0 if harness ever zeroes): last block detects
// old-899 ∈ {0, 0xAAAAAAAA} — robust to both, unambiguous for either init.

__global__ __launch_bounds__(256) void hmdl_fused(
    const float* __restrict__ logits,   // [4,1,540,540]
    const float* __restrict__ boxes,    // [4,64,7]
    const float* __restrict__ hmaps,    // [4,1,540,540]
    float* __restrict__ acc,            // 12 floats + 1 uint ticket
    float* __restrict__ out)
{
    __shared__ float s_cx[NBOX], s_cy[NBOX], s_c[NBOX], s_s[NBOX];
    __shared__ float s_hw[NBOX], s_hl[NBOX], s_hv[NBOX];
    __shared__ int   s_sel[NBOX];
    __shared__ int   s_nsel;
    __shared__ float s_red[3][4];

    const int b    = blockIdx.y;
    const int tile = blockIdx.x;
    const int tx0  = (tile % TPX) * TILE;
    const int ty0  = (tile / TPX) * TILE;
    const int tid  = threadIdx.x;

    // ---- per-box constants + tile culling (wave 0 only; order-preserving compact) ----
    if (tid < NBOX) {
        const float* bx = boxes + (b * NBOX + tid) * 7;
        float b0 = bx[0], b1 = bx[1], b3 = bx[3], b4 = bx[4], b5 = bx[5], b6 = bx[6];
        float cx = (b0 - (-54.0f)) / 0.2f;
        float cy = (b1 - (-54.0f)) / 0.2f;
        float hw = (b3 / 0.2f) * 0.5f;
        float hl = (b4 / 0.2f) * 0.5f;
        float c  = cosf(-b6);
        float s  = sinf(-b6);
        float hv = b5 / 5.0f;   // h / (PC_RANGE[5] + 2.0) = h / 5
        s_cx[tid] = cx; s_cy[tid] = cy; s_c[tid] = c; s_s[tid] = s;
        s_hw[tid] = hw; s_hl[tid] = hl; s_hv[tid] = hv;

        // exact AABB of the rotated rect
        float ex = fabsf(hw * c) + fabsf(hl * s);
        float ey = fabsf(hw * s) + fabsf(hl * c);
        bool hit = (cx + ex >= (float)tx0) && (cx - ex <= (float)(tx0 + TILE - 1)) &&
                   (cy + ey >= (float)ty0) && (cy - ey <= (float)(ty0 + TILE - 1));
        unsigned long long m = __ballot(hit);
        if (hit) {
            int pos = __popcll(m & ((1ull << tid) - 1ull));
            s_sel[pos] = tid;   // ascending j order preserved -> "last box wins" intact
        }
        if (tid == 0) s_nsel = __popcll(m);
    }
    __syncthreads();
    const int nsel = s_nsel;

    const float4* lg4 = (const float4*)logits;
    const float4* hm4 = (const float4*)hmaps;

    float a1 = 0.0f, a2 = 0.0f, ac = 0.0f;

    for (int q = tid; q < Q_PER_TILE; q += 256) {
        const int row = q / 9;          // 0..35
        const int c4  = q - row * 9;    // 0..8
        const int y   = ty0 + row;
        const int x   = tx0 + c4 * 4;
        const float xg = (float)x, yg = (float)y;

        const int idx4 = (b * YS + y) * XS4 + (tx0 >> 2) + c4;
        const float4 xv = lg4[idx4];
        const float4 hm = hm4[idx4];

        // rasterize 4 consecutive cells: last covering box wins; incremental lx/ly
        float g0 = 0.0f, g1 = 0.0f, g2 = 0.0f, g3 = 0.0f;
        for (int k = 0; k < nsel; ++k) {
            const int j = s_sel[k];
            const float cj = s_c[j], sj = s_s[j];
            const float hw = s_hw[j], hl = s_hl[j], hv = s_hv[j];
            const float dx = xg - s_cx[j];
            const float dy = yg - s_cy[j];
            float lx = dx * cj - dy * sj;
            float ly = dx * sj + dy * cj;
            if (fabsf(lx) <= hw && fabsf(ly) <= hl) g0 = hv;
            lx += cj; ly += sj;
            if (fabsf(lx) <= hw && fabsf(ly) <= hl) g1 = hv;
            lx += cj; ly += sj;
            if (fabsf(lx) <= hw && fabsf(ly) <= hl) g2 = hv;
            lx += cj; ly += sj;
            if (fabsf(lx) <= hw && fabsf(ly) <= hl) g3 = hv;
        }

        const float gts[4] = { g0, g1, g2, g3 };
        const float xvs[4] = { xv.x, xv.y, xv.z, xv.w };
        const float hms[4] = { hm.x, hm.y, hm.z, hm.w };

        #pragma unroll
        for (int m = 0; m < 4; ++m) {
            const float gt = gts[m];
            const float x_ = xvs[m];
            const bool  pos = gt > 0.0f;                 // neg == !pos
            const float weight = pos ? 5.0f : 0.1f;
            const bool  point = hms[m] > 0.0f;
            const float valid = (pos || point) ? 1.0f : 0.0f;

            // t = e^{-|x|};  sigmoid(x) = x>=0 ? 1/(1+t) : t/(1+t)
            const float t  = __expf(-fabsf(x_));
            const float bce = fmaxf(x_, 0.0f) - x_ * gt + __logf(1.0f + t);
            const float r  = 1.0f / (1.0f + t);
            const float p  = (x_ >= 0.0f) ? r : (t * r);
            const float pt = p * gt + (1.0f - p) * (1.0f - gt);
            const float aw = 0.25f * gt + 0.75f * (1.0f - gt);
            const float om = 1.0f - pt;
            const float fw = om * om * aw * weight;

            a1 += weight * bce * valid;
            a2 += fw * bce * valid;
            ac += valid;
        }
    }

    // ---- block reduction: wave64 shuffle + cross-wave LDS ----
    for (int off = 32; off > 0; off >>= 1) {
        a1 += __shfl_down(a1, off);
        a2 += __shfl_down(a2, off);
        ac += __shfl_down(ac, off);
    }
    const int wave = tid >> 6;
    if ((tid & 63) == 0) { s_red[0][wave] = a1; s_red[1][wave] = a2; s_red[2][wave] = ac; }
    __syncthreads();

    if (tid == 0) {
        float t1 = s_red[0][0] + s_red[0][1] + s_red[0][2] + s_red[0][3];
        float t2 = s_red[1][0] + s_red[1][1] + s_red[1][2] + s_red[1][3];
        float t3 = s_red[2][0] + s_red[2][1] + s_red[2][2] + s_red[2][3];

        // device-scope accumulate (L2 atomic ALU; pipelined, ~contention-free at 900 blocks)
        __hip_atomic_fetch_add(&acc[b],     t1, __ATOMIC_RELAXED, __HIP_MEMORY_SCOPE_AGENT);
        __hip_atomic_fetch_add(&acc[4 + b], t2, __ATOMIC_RELAXED, __HIP_MEMORY_SCOPE_AGENT);
        __hip_atomic_fetch_add(&acc[8 + b], t3, __ATOMIC_RELAXED, __HIP_MEMORY_SCOPE_AGENT);

        unsigned int* ticket = (unsigned int*)(acc + 12);
        unsigned int old = __hip_atomic_fetch_add(ticket, 1u,
                               __ATOMIC_ACQ_REL, __HIP_MEMORY_SCOPE_AGENT);
        unsigned int d = old - (unsigned int)(NBLK - 1);
        if (d == 0u || d == POISON_U32) {
            // I'm the last block: all producers' adds are visible (acq over their rel).
            float v[12];
            #pragma unroll
            for (int i = 0; i < 12; ++i)
                v[i] = __hip_atomic_load(&acc[i], __ATOMIC_RELAXED, __HIP_MEMORY_SCOPE_AGENT);
            float total = 0.0f, ns = 0.0f;
            #pragma unroll
            for (int k = 0; k < NB; ++k) {
                float cnt   = v[8 + k];
                float denom = fmaxf(cnt, 1.0f);
                float bl = v[k]     / denom;
                float fl = v[4 + k] / denom;
                bool has = cnt > 0.0f;
                total += has ? (0.5f * bl + 0.5f * fl) : 0.0f;
                ns    += has ? 1.0f : 0.0f;
            }
            out[0] = (ns > 0.0f) ? (total / fmaxf(ns, 1.0f)) : total;
        }
    }
}

extern "C" void kernel_launch(void* const* d_in, const int* in_sizes, int n_in,
                              void* d_out, int out_size, void* d_ws, size_t ws_size,
                              hipStream_t stream) {
    const float* logits = (const float*)d_in[0];
    const float* boxes  = (const float*)d_in[1];
    const float* hmaps  = (const float*)d_in[2];
    float* out = (float*)d_out;
    float* acc = (float*)d_ws;

    dim3 grid(NTILE, NB);
    hmdl_fused<<<grid, 256, 0, stream>>>(logits, boxes, hmaps, acc, out);
}

// Round 6
// 70.300 us; speedup vs baseline: 1.6229x; 1.6229x over previous
//
#include <hip/hip_runtime.h>
#include <math.h>

// Problem constants (from reference)
#define XS 540
#define YS 540
#define NB 4            // batch
#define NBOX 64
#define TILE 36         // 36x36 cells per block
#define TPX 15          // 540 / 36
#define NTILE (TPX * TPX)       // 225
#define Q_PER_TILE (36 * 9)     // 324 float4 groups per tile
#define XS4 (XS / 4)            // 135 float4 per row

// d_ws layout: float part[NB][NTILE][4] = { s1, s2, cnt, pad }.
// Every slot fully written by its owning block -> no zero-init needed.
//
// Architecture note (measured R3/R4/R5): two-kernel (part[] stores + tiny
// finalize dispatch) beats ALL single-kernel fusions on MI355X:
//   - flag spin-wait fusion: +13 us (cross-XCD acquire polling)
//   - ticket + same-line atomics: +46 us (~12-15 ns per same-line atomic x3600)
// Do not re-fuse.

__global__ __launch_bounds__(256) void hmdl_main(
    const float* __restrict__ logits,   // [4,1,540,540]
    const float* __restrict__ boxes,    // [4,64,7]
    const float* __restrict__ hmaps,    // [4,1,540,540]
    float4* __restrict__ part)          // [NB*NTILE]
{
    __shared__ float s_cx[NBOX], s_cy[NBOX], s_c[NBOX], s_s[NBOX];
    __shared__ float s_hw[NBOX], s_hl[NBOX], s_hv[NBOX];
    __shared__ int   s_sel[NBOX];
    __shared__ int   s_nsel;
    __shared__ float s_red[3][4];

    const int b    = blockIdx.y;
    const int tile = blockIdx.x;
    const int tx0  = (tile % TPX) * TILE;
    const int ty0  = (tile / TPX) * TILE;
    const int tid  = threadIdx.x;

    const float4* lg4 = (const float4*)logits;
    const float4* hm4 = (const float4*)hmaps;

    // ---- issue global loads FIRST (addresses independent of boxes) so the
    // cold-HBM latency (~900 cyc after the harness's cache-flushing poison
    // fill) overlaps the box preamble + cull below.
    const int q0   = tid;               // always < 324
    const int row0 = q0 / 9, c40 = q0 - row0 * 9;
    const int y0   = ty0 + row0;
    const int idxA = (b * YS + y0) * XS4 + (tx0 >> 2) + c40;
    const float4 xvA = lg4[idxA];
    const float4 hmA = hm4[idxA];

    const int  q1   = tid + 256;        // valid for tid < 68
    const bool hasQ1 = (q1 < Q_PER_TILE);
    const int row1 = q1 / 9, c41 = q1 - row1 * 9;
    const int y1   = ty0 + row1;
    const int idxB = (b * YS + (hasQ1 ? y1 : y0)) * XS4 + (tx0 >> 2) + (hasQ1 ? c41 : c40);
    const float4 xvB = lg4[idxB];
    const float4 hmB = hm4[idxB];

    // ---- per-box constants + tile culling (wave 0 only; order-preserving compact) ----
    if (tid < NBOX) {
        const float* bx = boxes + (b * NBOX + tid) * 7;
        float b0 = bx[0], b1 = bx[1], b3 = bx[3], b4 = bx[4], b5 = bx[5], b6 = bx[6];
        float cx = (b0 - (-54.0f)) / 0.2f;
        float cy = (b1 - (-54.0f)) / 0.2f;
        float hw = (b3 / 0.2f) * 0.5f;
        float hl = (b4 / 0.2f) * 0.5f;
        float c  = cosf(-b6);
        float s  = sinf(-b6);
        float hv = b5 / 5.0f;   // h / (PC_RANGE[5] + 2.0) = h / 5
        s_cx[tid] = cx; s_cy[tid] = cy; s_c[tid] = c; s_s[tid] = s;
        s_hw[tid] = hw; s_hl[tid] = hl; s_hv[tid] = hv;

        // exact AABB of the rotated rect
        float ex = fabsf(hw * c) + fabsf(hl * s);
        float ey = fabsf(hw * s) + fabsf(hl * c);
        bool hit = (cx + ex >= (float)tx0) && (cx - ex <= (float)(tx0 + TILE - 1)) &&
                   (cy + ey >= (float)ty0) && (cy - ey <= (float)(ty0 + TILE - 1));
        unsigned long long m = __ballot(hit);
        if (hit) {
            int pos = __popcll(m & ((1ull << tid) - 1ull));
            s_sel[pos] = tid;   // ascending j order preserved -> "last box wins" intact
        }
        if (tid == 0) s_nsel = __popcll(m);
    }
    __syncthreads();
    const int nsel = s_nsel;

    float a1 = 0.0f, a2 = 0.0f, ac = 0.0f;

    #pragma unroll
    for (int pass = 0; pass < 2; ++pass) {
        if (pass == 1 && !hasQ1) break;
        const int   x  = tx0 + (pass == 0 ? c40 : c41) * 4;
        const int   y  = (pass == 0 ? y0 : y1);
        const float4 xv = (pass == 0 ? xvA : xvB);
        const float4 hm = (pass == 0 ? hmA : hmB);
        const float xg = (float)x, yg = (float)y;

        // rasterize 4 consecutive cells: last covering box wins; incremental lx/ly
        float g0 = 0.0f, g1 = 0.0f, g2 = 0.0f, g3 = 0.0f;
        for (int k = 0; k < nsel; ++k) {
            const int j = s_sel[k];
            const float cj = s_c[j], sj = s_s[j];
            const float hw = s_hw[j], hl = s_hl[j], hv = s_hv[j];
            const float dx = xg - s_cx[j];
            const float dy = yg - s_cy[j];
            float lx = dx * cj - dy * sj;
            float ly = dx * sj + dy * cj;
            if (fabsf(lx) <= hw && fabsf(ly) <= hl) g0 = hv;
            lx += cj; ly += sj;
            if (fabsf(lx) <= hw && fabsf(ly) <= hl) g1 = hv;
            lx += cj; ly += sj;
            if (fabsf(lx) <= hw && fabsf(ly) <= hl) g2 = hv;
            lx += cj; ly += sj;
            if (fabsf(lx) <= hw && fabsf(ly) <= hl) g3 = hv;
        }

        const float gts[4] = { g0, g1, g2, g3 };
        const float xvs[4] = { xv.x, xv.y, xv.z, xv.w };
        const float hms[4] = { hm.x, hm.y, hm.z, hm.w };

        #pragma unroll
        for (int m = 0; m < 4; ++m) {
            const float gt = gts[m];
            const float x_ = xvs[m];
            const bool  pos = gt > 0.0f;                 // neg == !pos
            const float weight = pos ? 5.0f : 0.1f;
            const bool  point = hms[m] > 0.0f;
            const float valid = (pos || point) ? 1.0f : 0.0f;

            // t = e^{-|x|};  sigmoid(x) = x>=0 ? 1/(1+t) : t/(1+t)
            const float t  = __expf(-fabsf(x_));
            const float bce = fmaxf(x_, 0.0f) - x_ * gt + __logf(1.0f + t);
            const float r  = 1.0f / (1.0f + t);
            const float p  = (x_ >= 0.0f) ? r : (t * r);
            const float pt = p * gt + (1.0f - p) * (1.0f - gt);
            const float aw = 0.25f * gt + 0.75f * (1.0f - gt);
            const float om = 1.0f - pt;
            const float fw = om * om * aw * weight;

            a1 += weight * bce * valid;
            a2 += fw * bce * valid;
            ac += valid;
        }
    }

    // ---- block reduction: wave64 shuffle + cross-wave LDS ----
    for (int off = 32; off > 0; off >>= 1) {
        a1 += __shfl_down(a1, off);
        a2 += __shfl_down(a2, off);
        ac += __shfl_down(ac, off);
    }
    const int wave = tid >> 6;
    if ((tid & 63) == 0) { s_red[0][wave] = a1; s_red[1][wave] = a2; s_red[2][wave] = ac; }
    __syncthreads();
    if (tid == 0) {
        float t1 = s_red[0][0] + s_red[0][1] + s_red[0][2] + s_red[0][3];
        float t2 = s_red[1][0] + s_red[1][1] + s_red[1][2] + s_red[1][3];
        float t3 = s_red[2][0] + s_red[2][1] + s_red[2][2] + s_red[2][3];
        part[b * NTILE + tile] = make_float4(t1, t2, t3, 0.0f);
    }
}

// One block, 256 threads: wave w reduces sample w's 225 tile-partials.
__global__ __launch_bounds__(256) void hmdl_finalize(
    const float4* __restrict__ part, float* __restrict__ out)
{
    __shared__ float s_comb[NB];
    __shared__ float s_has[NB];

    const int tid  = threadIdx.x;
    const int b    = tid >> 6;
    const int lane = tid & 63;

    double d1 = 0.0, d2 = 0.0, d3 = 0.0;
    for (int t = lane; t < NTILE; t += 64) {
        float4 v = part[b * NTILE + t];
        d1 += (double)v.x; d2 += (double)v.y; d3 += (double)v.z;
    }
    for (int off = 32; off > 0; off >>= 1) {
        d1 += __shfl_down(d1, off);
        d2 += __shfl_down(d2, off);
        d3 += __shfl_down(d3, off);
    }
    if (lane == 0) {
        float cnt   = (float)d3;
        float denom = fmaxf(cnt, 1.0f);
        float bl = (float)d1 / denom;
        float fl = (float)d2 / denom;
        bool has = cnt > 0.0f;
        s_comb[b] = has ? (0.5f * bl + 0.5f * fl) : 0.0f;
        s_has[b]  = has ? 1.0f : 0.0f;
    }
    __syncthreads();
    if (tid == 0) {
        float total = s_comb[0] + s_comb[1] + s_comb[2] + s_comb[3];
        float ns    = s_has[0] + s_has[1] + s_has[2] + s_has[3];
        out[0] = (ns > 0.0f) ? (total / fmaxf(ns, 1.0f)) : total;
    }
}

extern "C" void kernel_launch(void* const* d_in, const int* in_sizes, int n_in,
                              void* d_out, int out_size, void* d_ws, size_t ws_size,
                              hipStream_t stream) {
    const float* logits = (const float*)d_in[0];
    const float* boxes  = (const float*)d_in[1];
    const float* hmaps  = (const float*)d_in[2];
    float* out = (float*)d_out;
    float4* part = (float4*)d_ws;

    dim3 grid(NTILE, NB);
    hmdl_main<<<grid, 256, 0, stream>>>(logits, boxes, hmaps, part);
    hmdl_finalize<<<1, 256, 0, stream>>>(part, out);
}

// Round 7
// 68.724 us; speedup vs baseline: 1.6602x; 1.0229x over previous
//
#include <hip/hip_runtime.h>
#include <math.h>

// Problem constants (from reference)
#define XS 540
#define YS 540
#define NB 4            // batch
#define NBOX 64
#define TILE_W 36       // 36 cells wide  = 9 float4
#define TILE_H 27       // 27 cells tall
#define TPX 15          // 540 / 36
#define TPY 20          // 540 / 27
#define NTILE (TPX * TPY)       // 300 tiles per sample
#define Q_PER_TILE (TILE_H * 9) // 243 float4 groups per tile (<= 256 threads)
#define XS4 (XS / 4)            // 135 float4 per row

// d_ws layout: float part[NB][NTILE][4] = { s1, s2, cnt, pad }.
// Every slot fully written by its owning block -> no zero-init needed.
//
// Architecture note (measured R3/R4/R5/R6): two-kernel (part[] stores + tiny
// finalize dispatch) beats ALL single-kernel fusions on MI355X:
//   - flag spin-wait fusion: +13 us (cross-XCD acquire polling)
//   - ticket + same-line atomics: +46 us (~12-15 ns per same-line atomic x3600)
//   - explicit load hoisting before the preamble: +2 us (wasted 2nd-pass loads)
// Do not re-fuse; do not re-hoist.

__global__ __launch_bounds__(256) void hmdl_main(
    const float* __restrict__ logits,   // [4,1,540,540]
    const float* __restrict__ boxes,    // [4,64,7]
    const float* __restrict__ hmaps,    // [4,1,540,540]
    float4* __restrict__ part)          // [NB*NTILE]
{
    __shared__ float s_cx[NBOX], s_cy[NBOX], s_c[NBOX], s_s[NBOX];
    __shared__ float s_hw[NBOX], s_hl[NBOX], s_hv[NBOX];
    __shared__ int   s_sel[NBOX];
    __shared__ int   s_nsel;
    __shared__ float s_red[3][4];

    const int b    = blockIdx.z;
    const int tx0  = blockIdx.x * TILE_W;
    const int ty0  = blockIdx.y * TILE_H;
    const int tid  = threadIdx.x;

    // ---- per-box constants + tile culling (wave 0 only; order-preserving compact) ----
    if (tid < NBOX) {
        const float* bx = boxes + (b * NBOX + tid) * 7;
        float b0 = bx[0], b1 = bx[1], b3 = bx[3], b4 = bx[4], b5 = bx[5], b6 = bx[6];
        float cx = (b0 - (-54.0f)) / 0.2f;
        float cy = (b1 - (-54.0f)) / 0.2f;
        float hw = (b3 / 0.2f) * 0.5f;
        float hl = (b4 / 0.2f) * 0.5f;
        float c  = cosf(-b6);
        float s  = sinf(-b6);
        float hv = b5 / 5.0f;   // h / (PC_RANGE[5] + 2.0) = h / 5
        s_cx[tid] = cx; s_cy[tid] = cy; s_c[tid] = c; s_s[tid] = s;
        s_hw[tid] = hw; s_hl[tid] = hl; s_hv[tid] = hv;

        // exact AABB of the rotated rect
        float ex = fabsf(hw * c) + fabsf(hl * s);
        float ey = fabsf(hw * s) + fabsf(hl * c);
        bool hit = (cx + ex >= (float)tx0) && (cx - ex <= (float)(tx0 + TILE_W - 1)) &&
                   (cy + ey >= (float)ty0) && (cy - ey <= (float)(ty0 + TILE_H - 1));
        unsigned long long m = __ballot(hit);
        if (hit) {
            int pos = __popcll(m & ((1ull << tid) - 1ull));
            s_sel[pos] = tid;   // ascending j order preserved -> "last box wins" intact
        }
        if (tid == 0) s_nsel = __popcll(m);
    }

    // ---- each thread owns exactly one float4 group (single pass, no tail loop)
    const bool  live = (tid < Q_PER_TILE);
    const int   q    = live ? tid : (Q_PER_TILE - 1);   // clamp: in-bounds load
    const int   row  = q / 9;
    const int   col  = q - row * 9;
    const int   y    = ty0 + row;
    const int   x    = tx0 + col * 4;
    const float xg   = (float)x, yg = (float)y;

    const float4* lg4 = (const float4*)logits;
    const float4* hm4 = (const float4*)hmaps;
    const int idx4 = (b * YS + y) * XS4 + (tx0 >> 2) + col;
    const float4 xv = lg4[idx4];
    const float4 hm = hm4[idx4];

    __syncthreads();
    const int nsel = s_nsel;

    // rasterize 4 consecutive cells: last covering box wins; incremental lx/ly
    float g0 = 0.0f, g1 = 0.0f, g2 = 0.0f, g3 = 0.0f;
    for (int k = 0; k < nsel; ++k) {
        const int j = s_sel[k];
        const float cj = s_c[j], sj = s_s[j];
        const float hw = s_hw[j], hl = s_hl[j], hv = s_hv[j];
        const float dx = xg - s_cx[j];
        const float dy = yg - s_cy[j];
        float lx = dx * cj - dy * sj;
        float ly = dx * sj + dy * cj;
        if (fabsf(lx) <= hw && fabsf(ly) <= hl) g0 = hv;
        lx += cj; ly += sj;
        if (fabsf(lx) <= hw && fabsf(ly) <= hl) g1 = hv;
        lx += cj; ly += sj;
        if (fabsf(lx) <= hw && fabsf(ly) <= hl) g2 = hv;
        lx += cj; ly += sj;
        if (fabsf(lx) <= hw && fabsf(ly) <= hl) g3 = hv;
    }

    float a1 = 0.0f, a2 = 0.0f, ac = 0.0f;
    {
        const float lv = live ? 1.0f : 0.0f;
        const float gts[4] = { g0, g1, g2, g3 };
        const float xvs[4] = { xv.x, xv.y, xv.z, xv.w };
        const float hms[4] = { hm.x, hm.y, hm.z, hm.w };

        #pragma unroll
        for (int m = 0; m < 4; ++m) {
            const float gt = gts[m];
            const float x_ = xvs[m];
            const bool  pos = gt > 0.0f;                 // neg == !pos
            const float weight = pos ? 5.0f : 0.1f;
            const bool  point = hms[m] > 0.0f;
            const float valid = ((pos || point) ? 1.0f : 0.0f) * lv;

            // t = e^{-|x|};  sigmoid(x) = x>=0 ? 1/(1+t) : t/(1+t)
            const float t  = __expf(-fabsf(x_));
            const float bce = fmaxf(x_, 0.0f) - x_ * gt + __logf(1.0f + t);
            const float r  = 1.0f / (1.0f + t);
            const float p  = (x_ >= 0.0f) ? r : (t * r);
            const float pt = p * gt + (1.0f - p) * (1.0f - gt);
            const float aw = 0.25f * gt + 0.75f * (1.0f - gt);
            const float om = 1.0f - pt;
            const float fw = om * om * aw * weight;

            a1 += weight * bce * valid;
            a2 += fw * bce * valid;
            ac += valid;
        }
    }

    // ---- block reduction: wave64 shuffle + cross-wave LDS ----
    for (int off = 32; off > 0; off >>= 1) {
        a1 += __shfl_down(a1, off);
        a2 += __shfl_down(a2, off);
        ac += __shfl_down(ac, off);
    }
    const int wave = tid >> 6;
    if ((tid & 63) == 0) { s_red[0][wave] = a1; s_red[1][wave] = a2; s_red[2][wave] = ac; }
    __syncthreads();
    if (tid == 0) {
        float t1 = s_red[0][0] + s_red[0][1] + s_red[0][2] + s_red[0][3];
        float t2 = s_red[1][0] + s_red[1][1] + s_red[1][2] + s_red[1][3];
        float t3 = s_red[2][0] + s_red[2][1] + s_red[2][2] + s_red[2][3];
        const int tile = blockIdx.y * TPX + blockIdx.x;
        part[b * NTILE + tile] = make_float4(t1, t2, t3, 0.0f);
    }
}

// One block, 256 threads: wave w reduces sample w's 300 tile-partials.
__global__ __launch_bounds__(256) void hmdl_finalize(
    const float4* __restrict__ part, float* __restrict__ out)
{
    __shared__ float s_comb[NB];
    __shared__ float s_has[NB];

    const int tid  = threadIdx.x;
    const int b    = tid >> 6;
    const int lane = tid & 63;

    double d1 = 0.0, d2 = 0.0, d3 = 0.0;
    for (int t = lane; t < NTILE; t += 64) {
        float4 v = part[b * NTILE + t];
        d1 += (double)v.x; d2 += (double)v.y; d3 += (double)v.z;
    }
    for (int off = 32; off > 0; off >>= 1) {
        d1 += __shfl_down(d1, off);
        d2 += __shfl_down(d2, off);
        d3 += __shfl_down(d3, off);
    }
    if (lane == 0) {
        float cnt   = (float)d3;
        float denom = fmaxf(cnt, 1.0f);
        float bl = (float)d1 / denom;
        float fl = (float)d2 / denom;
        bool has = cnt > 0.0f;
        s_comb[b] = has ? (0.5f * bl + 0.5f * fl) : 0.0f;
        s_has[b]  = has ? 1.0f : 0.0f;
    }
    __syncthreads();
    if (tid == 0) {
        float total = s_comb[0] + s_comb[1] + s_comb[2] + s_comb[3];
        float ns    = s_has[0] + s_has[1] + s_has[2] + s_has[3];
        out[0] = (ns > 0.0f) ? (total / fmaxf(ns, 1.0f)) : total;
    }
}

extern "C" void kernel_launch(void* const* d_in, const int* in_sizes, int n_in,
                              void* d_out, int out_size, void* d_ws, size_t ws_size,
                              hipStream_t stream) {
    const float* logits = (const float*)d_in[0];
    const float* boxes  = (const float*)d_in[1];
    const float* hmaps  = (const float*)d_in[2];
    float* out = (float*)d_out;
    float4* part = (float4*)d_ws;

    dim3 grid(TPX, TPY, NB);
    hmdl_main<<<grid, 256, 0, stream>>>(logits, boxes, hmaps, part);
    hmdl_finalize<<<1, 256, 0, stream>>>(part, out);
}